// Round 6
// baseline (196.802 us; speedup 1.0000x reference)
//
#include <hip/hip_runtime.h>
#include <hip/hip_bf16.h>

// KAN linear == GEMM M=8192, N=512, K=4096 (8 Chebyshev/silu feats per input,
// basis_0 folded into bias). Round 6: zero-LDS main loop + in-block split-K x4.
//  - 1024 blocks (4/CU), 4 waves/block each computing the SAME 64x64 tile on a
//    K-quarter -> 16 waves/CU for latency hiding, no main-loop barriers.
//  - A-frags generated per-lane in registers (one gen_chunk == one 16x16x32 A-frag)
//  - B-frags per-lane 16B loads from L2-resident W; nb==blockIdx&7 -> per-XCD W slice
//  - epilogue: LDS tree-reduce (3 barriers total), bias add, store.
#define IN_FEAT 512
#define OUT_FEAT 512
#define NTOK 8192
#define KDIM 4096

typedef short bf16x8 __attribute__((ext_vector_type(8)));
typedef float f32x4 __attribute__((ext_vector_type(4)));

static __device__ inline short f2bf(float f) {
    union { float f; unsigned u; } v; v.f = f;
    unsigned u = v.u;
    u += 0x7fffu + ((u >> 16) & 1u);   // RNE
    return (short)(u >> 16);
}

// pack two fp32 -> bf16 pair (round-half-up): 2 adds + v_perm
static __device__ inline unsigned pack2bf(float f0, float f1) {
    union { float f; unsigned u; } a, b; a.f = f0; b.f = f1;
    return __builtin_amdgcn_perm(b.u + 0x8000u, a.u + 0x8000u, 0x07060302u);
}

// 8 basis features of one (token,input): [silu(xc), xc, T2..T7] == one A-frag
static __device__ inline bf16x8 gen_chunk(float xv) {
    float xc = fminf(fmaxf(xv, -1.f), 1.f);
    float e  = __expf(-xc);
    float bse = xc * __builtin_amdgcn_rcpf(1.f + e);
    float b2 = 2.f * xc * xc - 1.f;
    float b3 = 2.f * xc * b2 - 1.f;
    float b4 = 2.f * xc * b3 - 1.f;
    float b5 = 2.f * xc * b4 - 1.f;
    float b6 = 2.f * xc * b5 - 1.f;
    float b7 = 2.f * xc * b6 - 1.f;
    union { uint4 u; bf16x8 v; } r;
    r.u.x = pack2bf(bse, xc);
    r.u.y = pack2bf(b2, b3);
    r.u.z = pack2bf(b4, b5);
    r.u.w = pack2bf(b6, b7);
    return r.v;
}

// ---------------- prep: W bf16 [512 x 4096] + folded bias ----------------
__global__ __launch_bounds__(256) void kan_prep(
    const float* __restrict__ coeff, const float* __restrict__ scale_base,
    const float* __restrict__ scale_spline, const float* __restrict__ base_bias,
    short* __restrict__ Wb, float* __restrict__ bias)
{
    int o = blockIdx.x;
    int tid = threadIdx.x;
    float local = 0.f;
#pragma unroll
    for (int rep = 0; rep < 2; ++rep) {
        int i = tid + rep * 256;
        size_t oi = (size_t)o * IN_FEAT + i;
        const float4* c4 = (const float4*)(coeff + oi * 8);
        float4 ca = c4[0], cb = c4[1];
        float ss = scale_spline[oi];
        float sb = scale_base[oi];
        local += base_bias[oi] + ss * ca.x;
        bf16x8 w;
        w[0] = f2bf(sb);
        w[1] = f2bf(ss * ca.y); w[2] = f2bf(ss * ca.z); w[3] = f2bf(ss * ca.w);
        w[4] = f2bf(ss * cb.x); w[5] = f2bf(ss * cb.y); w[6] = f2bf(ss * cb.z);
        w[7] = f2bf(ss * cb.w);
        *(bf16x8*)(Wb + (size_t)o * KDIM + (size_t)i * 8) = w;
    }
    __shared__ float red[4];
    for (int off = 32; off > 0; off >>= 1) local += __shfl_down(local, off, 64);
    int lane = tid & 63, wv = tid >> 6;
    if (lane == 0) red[wv] = local;
    __syncthreads();
    if (tid == 0) bias[o] = red[0] + red[1] + red[2] + red[3];
}

// ---------------- split-K zero-LDS-mainloop GEMM ----------------
#define RED_STRIDE 68   // 64 + 4 floats pad: epilogue LDS ~conflict-free

__global__ __launch_bounds__(256, 3) void kan_gemm6(
    const float* __restrict__ x, const short* __restrict__ Wb,
    const float* __restrict__ bias, float* __restrict__ out)
{
    __shared__ __align__(16) float red[2][64 * RED_STRIDE];   // 2 x 17 KB

    int tid = threadIdx.x;
    int nb = blockIdx.x & 7;         // 8 n-tiles -> distinct XCDs (W slice/XCD)
    int mb = blockIdx.x >> 3;        // 128 m-tiles
    int m0 = mb * 64, o0 = nb * 64;

    int lane = tid & 63, wv = tid >> 6;     // wv = K-quarter
    int qd = lane >> 4, ln15 = lane & 15;
    int inp0 = wv * 128;             // this wave's input range [inp0, inp0+128)

    f32x4 acc[4][4];
#pragma unroll
    for (int a = 0; a < 4; ++a)
#pragma unroll
        for (int b = 0; b < 4; ++b) acc[a][b] = (f32x4)0.f;

    // per-lane bases: x[row=m0+fm*16+ln15][col=inp0+sub*4+qd]
    const float* xg = x + (size_t)(m0 + ln15) * IN_FEAT + inp0 + qd;
    // B: W[o=o0+fn*16+ln15][k = (inp0+sub*4+qd)*8 .. +8]  (16 contiguous bytes)
    const short* bg = Wb + (size_t)(o0 + ln15) * KDIM + inp0 * 8 + qd * 8;

    // prefetch sub=0
    float  xn[4];
    bf16x8 bn[4];
#pragma unroll
    for (int fm = 0; fm < 4; ++fm) xn[fm] = xg[fm * 16 * IN_FEAT];
#pragma unroll
    for (int fn = 0; fn < 4; ++fn) bn[fn] = *(const bf16x8*)(bg + fn * 16 * KDIM);

#pragma unroll 2
    for (int sub = 0; sub < 32; ++sub) {     // 32 sub-iters x k=32 (4 inputs each)
        float  xc[4];
        bf16x8 bc[4];
#pragma unroll
        for (int i = 0; i < 4; ++i) { xc[i] = xn[i]; bc[i] = bn[i]; }
        if (sub < 31) {
            const float* xp = xg + (sub + 1) * 4;
            const short* bp = bg + (sub + 1) * 32;
#pragma unroll
            for (int fm = 0; fm < 4; ++fm) xn[fm] = xp[fm * 16 * IN_FEAT];
#pragma unroll
            for (int fn = 0; fn < 4; ++fn) bn[fn] = *(const bf16x8*)(bp + fn * 16 * KDIM);
        }
        bf16x8 af[4];
#pragma unroll
        for (int fm = 0; fm < 4; ++fm) af[fm] = gen_chunk(xc[fm]);
#pragma unroll
        for (int fm = 0; fm < 4; ++fm)
#pragma unroll
            for (int fn = 0; fn < 4; ++fn)
                acc[fm][fn] = __builtin_amdgcn_mfma_f32_16x16x32_bf16(
                    af[fm], bc[fn], acc[fm][fn], 0, 0, 0);
    }

    // ---- epilogue: tree-reduce the 4 K-quarter partials through LDS ----
    // C/D layout: row = qd*4+reg (m), col = ln15 (n). LDS layout [col][row], stride 68.
    auto wr_acc = [&](float* buf) {
#pragma unroll
        for (int fm = 0; fm < 4; ++fm)
#pragma unroll
            for (int fn = 0; fn < 4; ++fn)
                *(f32x4*)&buf[(fn * 16 + ln15) * RED_STRIDE + fm * 16 + qd * 4] = acc[fm][fn];
    };
    auto add_acc = [&](const float* buf) {
#pragma unroll
        for (int fm = 0; fm < 4; ++fm)
#pragma unroll
            for (int fn = 0; fn < 4; ++fn)
                acc[fm][fn] += *(const f32x4*)&buf[(fn * 16 + ln15) * RED_STRIDE + fm * 16 + qd * 4];
    };

    if (wv == 1) wr_acc(red[0]);
    if (wv == 3) wr_acc(red[1]);
    __syncthreads();
    if (wv == 0) add_acc(red[0]);    // 0 += 1
    if (wv == 2) add_acc(red[1]);    // 2 += 3
    __syncthreads();
    if (wv == 2) wr_acc(red[0]);
    __syncthreads();
    if (wv == 0) {
        add_acc(red[0]);             // 0 += (2+3)
#pragma unroll
        for (int fn = 0; fn < 4; ++fn) {
            int o = o0 + fn * 16 + ln15;
            float bv = bias[o];
#pragma unroll
            for (int fm = 0; fm < 4; ++fm) {
                int r0 = m0 + fm * 16 + qd * 4;
#pragma unroll
                for (int r = 0; r < 4; ++r)
                    out[(size_t)(r0 + r) * OUT_FEAT + o] = acc[fm][fn][r] + bv;
            }
        }
    }
}

extern "C" void kernel_launch(void* const* d_in, const int* in_sizes, int n_in,
                              void* d_out, int out_size, void* d_ws, size_t ws_size,
                              hipStream_t stream) {
    const float* x            = (const float*)d_in[0];
    const float* coeff        = (const float*)d_in[1];
    const float* scale_base   = (const float*)d_in[2];
    const float* scale_spline = (const float*)d_in[3];
    const float* base_bias    = (const float*)d_in[4];
    float* out = (float*)d_out;

    short* Wb   = (short*)d_ws;                                  // 4 MB
    float* bias = (float*)((char*)d_ws + (size_t)OUT_FEAT * KDIM * 2);

    kan_prep<<<OUT_FEAT, 256, 0, stream>>>(coeff, scale_base, scale_spline, base_bias, Wb, bias);
    kan_gemm6<<<(NTOK / 64) * (OUT_FEAT / 64), 256, 0, stream>>>(x, Wb, bias, out);
}

// Round 7
// 195.975 us; speedup vs baseline: 1.0042x; 1.0042x over previous
//
#include <hip/hip_runtime.h>
#include <hip/hip_bf16.h>

// KAN linear == GEMM M=8192, N=512, K=4096 (8 Chebyshev/silu feats per input,
// basis_0 folded into bias). Round 7: zero-LDS main loop + in-block split-K x4
// + DEPTH-4 register prefetch pipeline (R6 stalled at distance 1 vs ~200cyc L2).
//  - 1024 blocks, 4 waves/block on the SAME 64x64 tile, one K-quarter each.
//  - A-frags generated per-lane in registers (one gen_chunk == one 16x16x32 A-frag)
//  - B-frags per-lane 16B loads from L2-resident W (100% line efficiency)
//  - epilogue: LDS tree-reduce (3 barriers total), bias add, store.
#define IN_FEAT 512
#define OUT_FEAT 512
#define NTOK 8192
#define KDIM 4096
#define PF 4            // prefetch depth (sub-iters)

typedef short bf16x8 __attribute__((ext_vector_type(8)));
typedef float f32x4 __attribute__((ext_vector_type(4)));

static __device__ inline short f2bf(float f) {
    union { float f; unsigned u; } v; v.f = f;
    unsigned u = v.u;
    u += 0x7fffu + ((u >> 16) & 1u);   // RNE
    return (short)(u >> 16);
}

// pack two fp32 -> bf16 pair (round-half-up): 2 adds + v_perm
static __device__ inline unsigned pack2bf(float f0, float f1) {
    union { float f; unsigned u; } a, b; a.f = f0; b.f = f1;
    return __builtin_amdgcn_perm(b.u + 0x8000u, a.u + 0x8000u, 0x07060302u);
}

// 8 basis features of one (token,input): [silu(xc), xc, T2..T7] == one A-frag
static __device__ inline bf16x8 gen_chunk(float xv) {
    float xc = fminf(fmaxf(xv, -1.f), 1.f);
    float e  = __expf(-xc);
    float bse = xc * __builtin_amdgcn_rcpf(1.f + e);
    float b2 = 2.f * xc * xc - 1.f;
    float b3 = 2.f * xc * b2 - 1.f;
    float b4 = 2.f * xc * b3 - 1.f;
    float b5 = 2.f * xc * b4 - 1.f;
    float b6 = 2.f * xc * b5 - 1.f;
    float b7 = 2.f * xc * b6 - 1.f;
    union { uint4 u; bf16x8 v; } r;
    r.u.x = pack2bf(bse, xc);
    r.u.y = pack2bf(b2, b3);
    r.u.z = pack2bf(b4, b5);
    r.u.w = pack2bf(b6, b7);
    return r.v;
}

// ---------------- prep: W bf16 [512 x 4096] + folded bias ----------------
__global__ __launch_bounds__(256) void kan_prep(
    const float* __restrict__ coeff, const float* __restrict__ scale_base,
    const float* __restrict__ scale_spline, const float* __restrict__ base_bias,
    short* __restrict__ Wb, float* __restrict__ bias)
{
    int o = blockIdx.x;
    int tid = threadIdx.x;
    float local = 0.f;
#pragma unroll
    for (int rep = 0; rep < 2; ++rep) {
        int i = tid + rep * 256;
        size_t oi = (size_t)o * IN_FEAT + i;
        const float4* c4 = (const float4*)(coeff + oi * 8);
        float4 ca = c4[0], cb = c4[1];
        float ss = scale_spline[oi];
        float sb = scale_base[oi];
        local += base_bias[oi] + ss * ca.x;
        bf16x8 w;
        w[0] = f2bf(sb);
        w[1] = f2bf(ss * ca.y); w[2] = f2bf(ss * ca.z); w[3] = f2bf(ss * ca.w);
        w[4] = f2bf(ss * cb.x); w[5] = f2bf(ss * cb.y); w[6] = f2bf(ss * cb.z);
        w[7] = f2bf(ss * cb.w);
        *(bf16x8*)(Wb + (size_t)o * KDIM + (size_t)i * 8) = w;
    }
    __shared__ float red[4];
    for (int off = 32; off > 0; off >>= 1) local += __shfl_down(local, off, 64);
    int lane = tid & 63, wv = tid >> 6;
    if (lane == 0) red[wv] = local;
    __syncthreads();
    if (tid == 0) bias[o] = red[0] + red[1] + red[2] + red[3];
}

// ---------------- split-K zero-LDS-mainloop GEMM, depth-4 pipeline ----------------
#define RED_STRIDE 68   // 64 + 4 floats pad: epilogue LDS ~conflict-free

__global__ __launch_bounds__(256, 2) void kan_gemm7(
    const float* __restrict__ x, const short* __restrict__ Wb,
    const float* __restrict__ bias, float* __restrict__ out)
{
    __shared__ __align__(16) float red[2][64 * RED_STRIDE];   // 2 x 17 KB

    int tid = threadIdx.x;
    int nb = blockIdx.x & 7;         // 8 n-tiles -> distinct XCDs (W slice/XCD)
    int mb = blockIdx.x >> 3;        // 128 m-tiles
    int m0 = mb * 64, o0 = nb * 64;

    int lane = tid & 63, wv = tid >> 6;     // wv = K-quarter
    int qd = lane >> 4, ln15 = lane & 15;
    int inp0 = wv * 128;             // this wave's input range [inp0, inp0+128)

    f32x4 acc[4][4];
#pragma unroll
    for (int a = 0; a < 4; ++a)
#pragma unroll
        for (int b = 0; b < 4; ++b) acc[a][b] = (f32x4)0.f;

    // per-lane bases: x[row=m0+fm*16+ln15][col=inp0+sub*4+qd]
    const float* xg = x + (size_t)(m0 + ln15) * IN_FEAT + inp0 + qd;
    // B: W[o=o0+fn*16+ln15][k = (inp0+sub*4+qd)*8 .. +8]  (16 contiguous bytes)
    const short* bg = Wb + (size_t)(o0 + ln15) * KDIM + inp0 * 8 + qd * 8;

    // circular prefetch slots [PF][4]
    float  xs[PF][4];
    bf16x8 bs[PF][4];
#pragma unroll
    for (int s = 0; s < PF; ++s) {
        const float* xp = xg + s * 4;
        const short* bp = bg + s * 32;
#pragma unroll
        for (int fm = 0; fm < 4; ++fm) xs[s][fm] = xp[fm * 16 * IN_FEAT];
#pragma unroll
        for (int fn = 0; fn < 4; ++fn) bs[s][fn] = *(const bf16x8*)(bp + fn * 16 * KDIM);
    }

#pragma unroll 4
    for (int sub = 0; sub < 32; ++sub) {     // 32 sub-iters x k=32 (4 inputs each)
        int c = sub & (PF - 1);
        // consume slot c (SSA: values live in regs; slot rewritten below)
        bf16x8 af[4], bc[4];
        float  xc[4];
#pragma unroll
        for (int i = 0; i < 4; ++i) { xc[i] = xs[c][i]; bc[i] = bs[c][i]; }
        // refill slot c for sub+PF (in flight across next PF-1 sub-iters)
        if (sub < 32 - PF) {
            const float* xp = xg + (sub + PF) * 4;
            const short* bp = bg + (sub + PF) * 32;
#pragma unroll
            for (int fm = 0; fm < 4; ++fm) xs[c][fm] = xp[fm * 16 * IN_FEAT];
#pragma unroll
            for (int fn = 0; fn < 4; ++fn) bs[c][fn] = *(const bf16x8*)(bp + fn * 16 * KDIM);
        }
#pragma unroll
        for (int fm = 0; fm < 4; ++fm) af[fm] = gen_chunk(xc[fm]);
#pragma unroll
        for (int fm = 0; fm < 4; ++fm)
#pragma unroll
            for (int fn = 0; fn < 4; ++fn)
                acc[fm][fn] = __builtin_amdgcn_mfma_f32_16x16x32_bf16(
                    af[fm], bc[fn], acc[fm][fn], 0, 0, 0);
    }

    // ---- epilogue: tree-reduce the 4 K-quarter partials through LDS ----
    // C/D layout: row = qd*4+reg (m), col = ln15 (n). LDS layout [col][row], stride 68.
    auto wr_acc = [&](float* buf) {
#pragma unroll
        for (int fm = 0; fm < 4; ++fm)
#pragma unroll
            for (int fn = 0; fn < 4; ++fn)
                *(f32x4*)&buf[(fn * 16 + ln15) * RED_STRIDE + fm * 16 + qd * 4] = acc[fm][fn];
    };
    auto add_acc = [&](const float* buf) {
#pragma unroll
        for (int fm = 0; fm < 4; ++fm)
#pragma unroll
            for (int fn = 0; fn < 4; ++fn)
                acc[fm][fn] += *(const f32x4*)&buf[(fn * 16 + ln15) * RED_STRIDE + fm * 16 + qd * 4];
    };

    if (wv == 1) wr_acc(red[0]);
    if (wv == 3) wr_acc(red[1]);
    __syncthreads();
    if (wv == 0) add_acc(red[0]);    // 0 += 1
    if (wv == 2) add_acc(red[1]);    // 2 += 3
    __syncthreads();
    if (wv == 2) wr_acc(red[0]);
    __syncthreads();
    if (wv == 0) {
        add_acc(red[0]);             // 0 += (2+3)
#pragma unroll
        for (int fn = 0; fn < 4; ++fn) {
            int o = o0 + fn * 16 + ln15;
            float bv = bias[o];
#pragma unroll
            for (int fm = 0; fm < 4; ++fm) {
                int r0 = m0 + fm * 16 + qd * 4;
#pragma unroll
                for (int r = 0; r < 4; ++r)
                    out[(size_t)(r0 + r) * OUT_FEAT + o] = acc[fm][fn][r] + bv;
            }
        }
    }
}

extern "C" void kernel_launch(void* const* d_in, const int* in_sizes, int n_in,
                              void* d_out, int out_size, void* d_ws, size_t ws_size,
                              hipStream_t stream) {
    const float* x            = (const float*)d_in[0];
    const float* coeff        = (const float*)d_in[1];
    const float* scale_base   = (const float*)d_in[2];
    const float* scale_spline = (const float*)d_in[3];
    const float* base_bias    = (const float*)d_in[4];
    float* out = (float*)d_out;

    short* Wb   = (short*)d_ws;                                  // 4 MB
    float* bias = (float*)((char*)d_ws + (size_t)OUT_FEAT * KDIM * 2);

    kan_prep<<<OUT_FEAT, 256, 0, stream>>>(coeff, scale_base, scale_spline, base_bias, Wb, bias);
    kan_gemm7<<<(NTOK / 64) * (OUT_FEAT / 64), 256, 0, stream>>>(x, Wb, bias, out);
}

// Round 8
// 139.249 us; speedup vs baseline: 1.4133x; 1.4074x over previous
//
#include <hip/hip_runtime.h>
#include <hip/hip_bf16.h>

// KAN linear == GEMM M=8192, N=512, K=4096 (8 Chebyshev/silu feats per input,
// basis_0 folded into bias). Round 8: R3 skeleton (dbuf LDS, 1 barrier/iter,
// global_load_lds B w/ XOR swizzle) but A-gen feeds from a tiny transposed
// x-slab in LDS (ds_read_b32, 2-way max) -> A-frags built in registers, never
// staged. R5-R7's per-lane global x loads (64 lines/instr) killed the TA path.
#define IN_FEAT 512
#define OUT_FEAT 512
#define NTOK 8192
#define KDIM 4096

#define BM 64
#define BN 128
#define BK 64          // 8 inputs x 8 basis feats per K-iter
#define XPAD 72        // x-slab row stride (floats): conflict-free slab reads

typedef short bf16x8 __attribute__((ext_vector_type(8)));
typedef float f32x4 __attribute__((ext_vector_type(4)));

static __device__ inline short f2bf(float f) {
    union { float f; unsigned u; } v; v.f = f;
    unsigned u = v.u;
    u += 0x7fffu + ((u >> 16) & 1u);   // RNE
    return (short)(u >> 16);
}

// pack two fp32 -> bf16 pair (round-half-up): 2 adds + v_perm
static __device__ inline unsigned pack2bf(float f0, float f1) {
    union { float f; unsigned u; } a, b; a.f = f0; b.f = f1;
    return __builtin_amdgcn_perm(b.u + 0x8000u, a.u + 0x8000u, 0x07060302u);
}

// 8 basis features of one (token,input): [silu(xc), xc, T2..T7] == one A-frag
static __device__ inline bf16x8 gen_chunk(float xv) {
    float xc = fminf(fmaxf(xv, -1.f), 1.f);
    float e  = __expf(-xc);
    float bse = xc * __builtin_amdgcn_rcpf(1.f + e);
    float b2 = 2.f * xc * xc - 1.f;
    float b3 = 2.f * xc * b2 - 1.f;
    float b4 = 2.f * xc * b3 - 1.f;
    float b5 = 2.f * xc * b4 - 1.f;
    float b6 = 2.f * xc * b5 - 1.f;
    float b7 = 2.f * xc * b6 - 1.f;
    union { uint4 u; bf16x8 v; } r;
    r.u.x = pack2bf(bse, xc);
    r.u.y = pack2bf(b2, b3);
    r.u.z = pack2bf(b4, b5);
    r.u.w = pack2bf(b6, b7);
    return r.v;
}

static __device__ inline void gload_lds16(const short* g, short* l) {
    __builtin_amdgcn_global_load_lds(
        (const __attribute__((address_space(1))) unsigned int*)g,
        (__attribute__((address_space(3))) unsigned int*)l,
        16, 0, 0);
}

// ---------------- prep: W bf16 [512 x 4096] + folded bias ----------------
__global__ __launch_bounds__(256) void kan_prep(
    const float* __restrict__ coeff, const float* __restrict__ scale_base,
    const float* __restrict__ scale_spline, const float* __restrict__ base_bias,
    short* __restrict__ Wb, float* __restrict__ bias)
{
    int o = blockIdx.x;
    int tid = threadIdx.x;
    float local = 0.f;
#pragma unroll
    for (int rep = 0; rep < 2; ++rep) {
        int i = tid + rep * 256;
        size_t oi = (size_t)o * IN_FEAT + i;
        const float4* c4 = (const float4*)(coeff + oi * 8);
        float4 ca = c4[0], cb = c4[1];
        float ss = scale_spline[oi];
        float sb = scale_base[oi];
        local += base_bias[oi] + ss * ca.x;
        bf16x8 w;
        w[0] = f2bf(sb);
        w[1] = f2bf(ss * ca.y); w[2] = f2bf(ss * ca.z); w[3] = f2bf(ss * ca.w);
        w[4] = f2bf(ss * cb.x); w[5] = f2bf(ss * cb.y); w[6] = f2bf(ss * cb.z);
        w[7] = f2bf(ss * cb.w);
        *(bf16x8*)(Wb + (size_t)o * KDIM + (size_t)i * 8) = w;
    }
    __shared__ float red[4];
    for (int off = 32; off > 0; off >>= 1) local += __shfl_down(local, off, 64);
    int lane = tid & 63, wv = tid >> 6;
    if (lane == 0) red[wv] = local;
    __syncthreads();
    if (tid == 0) bias[o] = red[0] + red[1] + red[2] + red[3];
}

// ---------------- fused GEMM: dbuf B-LDS + transposed x-slab ----------------
__global__ __launch_bounds__(256, 4) void kan_gemm8(
    const float* __restrict__ x, const short* __restrict__ Wb,
    const float* __restrict__ bias, float* __restrict__ out)
{
    __shared__ __align__(16) short Bs[2][BN * BK];     // 2 x 16 KB
    __shared__ __align__(16) float xslab[2][8 * XPAD]; // 2 x 2.25 KB, [inp][row]

    int tid = threadIdx.x;
    int nb = blockIdx.x & 3;         // 4 n-tiles; XCD j sees only nb=j&3 -> 1MB W slice/XCD
    int mb = blockIdx.x >> 2;        // 128 m-tiles
    int m0 = mb * BM, o0 = nb * BN;

    int lane = tid & 63, wv = tid >> 6;
    int wm = wv & 1, wn = wv >> 1;   // wave tile 32m x 64n
    int qd = lane >> 4, ln15 = lane & 15;

    f32x4 acc[2][4];
#pragma unroll
    for (int a = 0; a < 2; ++a)
#pragma unroll
        for (int b = 0; b < 4; ++b) acc[a][b] = (f32x4)0.f;

    // ---- B DMA: wave wv stages rows [wv*32, wv*32+32) in 4 calls of 8 rows ----
    int rg = lane >> 3;              // row-in-group 0..7
    int c_log = (lane & 7) ^ rg;     // fetch logical chunk so phys (lane&7) is swizzled
    const short* Bg = Wb + (size_t)(o0 + wv * 32 + rg) * KDIM + c_log * 8;

    // ---- x staging: thread t loads float2 x[m0 + t/4][it*8 + (t&3)*2] ----
    int xrow = tid >> 2, xc0 = (tid & 3) * 2;
    const float* xg = x + (size_t)(m0 + xrow) * IN_FEAT + xc0;
    int so0 = xc0 * XPAD + xrow, so1 = (xc0 + 1) * XPAD + xrow;

    // ---- prologue: stage iter 0 ----
    {
#pragma unroll
        for (int j = 0; j < 4; ++j)
            gload_lds16(Bg + (size_t)j * 8 * KDIM, &Bs[0][(wv * 32 + j * 8) * BK]);
        float2 xv = *(const float2*)xg;
        xslab[0][so0] = xv.x;
        xslab[0][so1] = xv.y;
    }

    int cur = 0;
    for (int it = 0; it < IN_FEAT / 8; ++it, cur ^= 1) {   // 64 iters
        __syncthreads();             // buf[cur] ready (DMA+writes drained); buf[nxt] free
        if (it < IN_FEAT / 8 - 1) {
            int nxt = cur ^ 1;
            const short* bsrc = Bg + (it + 1) * BK;
#pragma unroll
            for (int j = 0; j < 4; ++j)
                gload_lds16(bsrc + (size_t)j * 8 * KDIM, &Bs[nxt][(wv * 32 + j * 8) * BK]);
            float2 xv = *(const float2*)(xg + (it + 1) * 8);
            xslab[nxt][so0] = xv.x;
            xslab[nxt][so1] = xv.y;
        }
        // ---- compute on buf[cur] ----
#pragma unroll
        for (int kq = 0; kq < 2; ++kq) {
            int inp = kq * 4 + qd;
            bf16x8 af[2], bfv[4];
#pragma unroll
            for (int f = 0; f < 2; ++f) {
                float xv_ = xslab[cur][inp * XPAD + wm * 32 + f * 16 + ln15];
                af[f] = gen_chunk(xv_);
            }
#pragma unroll
            for (int fn = 0; fn < 4; ++fn) {
                int row = wn * 64 + fn * 16 + ln15;
                bfv[fn] = *(const bf16x8*)&Bs[cur][row * BK + ((kq * 4 + qd) ^ (row & 7)) * 8];
            }
#pragma unroll
            for (int f = 0; f < 2; ++f)
#pragma unroll
                for (int fn = 0; fn < 4; ++fn)
                    acc[f][fn] = __builtin_amdgcn_mfma_f32_16x16x32_bf16(
                        af[f], bfv[fn], acc[f][fn], 0, 0, 0);
        }
    }

    // ---- epilogue: C/D row = qd*4+reg, col = ln15 ----
#pragma unroll
    for (int fn = 0; fn < 4; ++fn) {
        int o = o0 + wn * 64 + fn * 16 + ln15;
        float bv = bias[o];
#pragma unroll
        for (int f = 0; f < 2; ++f) {
            int r0 = m0 + wm * 32 + f * 16 + qd * 4;
#pragma unroll
            for (int r = 0; r < 4; ++r)
                out[(size_t)(r0 + r) * OUT_FEAT + o] = acc[f][fn][r] + bv;
        }
    }
}

extern "C" void kernel_launch(void* const* d_in, const int* in_sizes, int n_in,
                              void* d_out, int out_size, void* d_ws, size_t ws_size,
                              hipStream_t stream) {
    const float* x            = (const float*)d_in[0];
    const float* coeff        = (const float*)d_in[1];
    const float* scale_base   = (const float*)d_in[2];
    const float* scale_spline = (const float*)d_in[3];
    const float* base_bias    = (const float*)d_in[4];
    float* out = (float*)d_out;

    short* Wb   = (short*)d_ws;                                  // 4 MB
    float* bias = (float*)((char*)d_ws + (size_t)OUT_FEAT * KDIM * 2);

    kan_prep<<<OUT_FEAT, 256, 0, stream>>>(coeff, scale_base, scale_spline, base_bias, Wb, bias);
    kan_gemm8<<<(NTOK / BM) * (OUT_FEAT / BN), 256, 0, stream>>>(x, Wb, bias, out);
}

// Round 9
// 132.141 us; speedup vs baseline: 1.4893x; 1.0538x over previous
//
#include <hip/hip_runtime.h>
#include <hip/hip_bf16.h>

// KAN linear == GEMM M=8192, N=512, K=4096 (8 Chebyshev/silu feats per input,
// basis_0 folded into bias). Round 9: 32x32x16 MFMA w/ 64x64 wave tiles
// (halves LDS-bytes/FLOP and gen/FLOP vs R8's 16x16x32), in-block split-K x2
// to keep grid=512 (2 blk/CU). A-frags register-generated (1 gen_chunk == one
// 32x32x16 A-frag); B via global_load_lds + XOR swizzle; x via tiny LDS slab.
#define IN_FEAT 512
#define OUT_FEAT 512
#define NTOK 8192
#define KDIM 4096

typedef short bf16x8 __attribute__((ext_vector_type(8)));
typedef float f32x4 __attribute__((ext_vector_type(4)));
typedef float f32x16 __attribute__((ext_vector_type(16)));

static __device__ inline short f2bf(float f) {
    union { float f; unsigned u; } v; v.f = f;
    unsigned u = v.u;
    u += 0x7fffu + ((u >> 16) & 1u);   // RNE
    return (short)(u >> 16);
}

static __device__ inline unsigned pack2bf(float f0, float f1) {
    union { float f; unsigned u; } a, b; a.f = f0; b.f = f1;
    return __builtin_amdgcn_perm(b.u + 0x8000u, a.u + 0x8000u, 0x07060302u);
}

// 8 basis features of one (token,input): [silu(xc), xc, T2..T7] == one A-frag (k=8)
static __device__ inline bf16x8 gen_chunk(float xv) {
    float xc = fminf(fmaxf(xv, -1.f), 1.f);
    float e  = __expf(-xc);
    float bse = xc * __builtin_amdgcn_rcpf(1.f + e);
    float b2 = 2.f * xc * xc - 1.f;
    float b3 = 2.f * xc * b2 - 1.f;
    float b4 = 2.f * xc * b3 - 1.f;
    float b5 = 2.f * xc * b4 - 1.f;
    float b6 = 2.f * xc * b5 - 1.f;
    float b7 = 2.f * xc * b6 - 1.f;
    union { uint4 u; bf16x8 v; } r;
    r.u.x = pack2bf(bse, xc);
    r.u.y = pack2bf(b2, b3);
    r.u.z = pack2bf(b4, b5);
    r.u.w = pack2bf(b6, b7);
    return r.v;
}

static __device__ inline void gload_lds16(const short* g, short* l) {
    __builtin_amdgcn_global_load_lds(
        (const __attribute__((address_space(1))) unsigned int*)g,
        (__attribute__((address_space(3))) unsigned int*)l,
        16, 0, 0);
}

// ---------------- prep: W bf16 [512 x 4096] + folded bias ----------------
__global__ __launch_bounds__(256) void kan_prep(
    const float* __restrict__ coeff, const float* __restrict__ scale_base,
    const float* __restrict__ scale_spline, const float* __restrict__ base_bias,
    short* __restrict__ Wb, float* __restrict__ bias)
{
    int o = blockIdx.x;
    int tid = threadIdx.x;
    float local = 0.f;
#pragma unroll
    for (int rep = 0; rep < 2; ++rep) {
        int i = tid + rep * 256;
        size_t oi = (size_t)o * IN_FEAT + i;
        const float4* c4 = (const float4*)(coeff + oi * 8);
        float4 ca = c4[0], cb = c4[1];
        float ss = scale_spline[oi];
        float sb = scale_base[oi];
        local += base_bias[oi] + ss * ca.x;
        bf16x8 w;
        w[0] = f2bf(sb);
        w[1] = f2bf(ss * ca.y); w[2] = f2bf(ss * ca.z); w[3] = f2bf(ss * ca.w);
        w[4] = f2bf(ss * cb.x); w[5] = f2bf(ss * cb.y); w[6] = f2bf(ss * cb.z);
        w[7] = f2bf(ss * cb.w);
        *(bf16x8*)(Wb + (size_t)o * KDIM + (size_t)i * 8) = w;
    }
    __shared__ float red[4];
    for (int off = 32; off > 0; off >>= 1) local += __shfl_down(local, off, 64);
    int lane = tid & 63, wv = tid >> 6;
    if (lane == 0) red[wv] = local;
    __syncthreads();
    if (tid == 0) bias[o] = red[0] + red[1] + red[2] + red[3];
}

// ---------------- 32x32x16 fused GEMM, in-block split-K x2 ----------------
#define RSTR 67   // epilogue reduce stride (floats): (lane*67)%32 distinct -> 2-way max

__global__ __launch_bounds__(256, 2) void kan_gemm9(
    const float* __restrict__ x, const short* __restrict__ Wb,
    const float* __restrict__ bias, float* __restrict__ out)
{
    __shared__ __align__(16) short Bs[2][2][128 * 64];  // [buf][khalf][row*64] 64 KB
    __shared__ __align__(16) float xsl[2][16 * 64];     // [buf][inp*64+row]    8 KB

    int tid = threadIdx.x;
    int nb = blockIdx.x & 3;         // XCD j sees nb=j&3 -> 1 MB W slice per XCD L2
    int mb = blockIdx.x >> 2;        // 128 m-tiles
    int m0 = mb * 64, o0 = nb * 128;

    int lane = tid & 63, wv = tid >> 6;
    int wn = wv & 1, kk = wv >> 1;   // wave = 64m x 64n on K-half kk
    int l31 = lane & 31, half = lane >> 5;

    f32x16 acc[2][2];                // [fm][fn], 32x32 each
#pragma unroll
    for (int a = 0; a < 2; ++a)
#pragma unroll
        for (int b = 0; b < 2; ++b) acc[a][b] = (f32x16)0.f;

    // B DMA: wave wv stages rows [wv*32,+32) for BOTH k-halves, 4 calls each
    int rg = lane >> 3;
    int c_log = (lane & 7) ^ rg;     // logical chunk fetched so phys (lane&7) is swizzled
    const short* Bg0 = Wb + (size_t)(o0 + wv * 32 + rg) * KDIM + c_log * 8;  // khalf 0
    const short* Bg1 = Bg0 + 2048;                                            // khalf 1

    // x staging: thread -> (row, quarter); float4 covers 4 inputs of one k-half
    int xrow = tid >> 2, p = tid & 3;
    int xh = p >> 1, xq = p & 1;
    const float* xg = x + (size_t)(m0 + xrow) * IN_FEAT + xh * 256 + xq * 4;
    int sbase = (xh * 8 + xq * 4) * 64 + xrow;

#define STAGE(buf, it)                                                        \
    {                                                                         \
        const short* b0_ = Bg0 + (it) * 64;                                   \
        const short* b1_ = Bg1 + (it) * 64;                                   \
        _Pragma("unroll")                                                     \
        for (int j = 0; j < 4; ++j) {                                         \
            gload_lds16(b0_ + (size_t)j * 8 * KDIM, &Bs[buf][0][(wv * 32 + j * 8) * 64]); \
            gload_lds16(b1_ + (size_t)j * 8 * KDIM, &Bs[buf][1][(wv * 32 + j * 8) * 64]); \
        }                                                                     \
        float4 v_ = *(const float4*)(xg + (it) * 8);                          \
        xsl[buf][sbase]       = v_.x;                                         \
        xsl[buf][sbase + 64]  = v_.y;                                         \
        xsl[buf][sbase + 128] = v_.z;                                         \
        xsl[buf][sbase + 192] = v_.w;                                         \
    }

    STAGE(0, 0);
    int cur = 0;
    for (int it = 0; it < 32; ++it, cur ^= 1) {   // each wave: K-half = 2048 = 32 x 64
        __syncthreads();             // buf[cur] ready (DMA+writes drained); buf[nxt] free
        if (it < 31) { int nxt = cur ^ 1; STAGE(nxt, it + 1); }
#pragma unroll
        for (int istep = 0; istep < 4; ++istep) {   // 4 k-steps of 16 (2 inputs each)
            int clog = istep * 2 + half;            // this lane's 16B chunk (k=half*8..+8)
            bf16x8 bfr[2], af[2];
#pragma unroll
            for (int fn = 0; fn < 2; ++fn) {
                int row = wn * 64 + fn * 32 + l31;
                bfr[fn] = *(const bf16x8*)&Bs[cur][kk][row * 64 + (clog ^ (row & 7)) * 8];
            }
            int inp = kk * 8 + istep * 2 + half;    // local input index in the 16-slab
#pragma unroll
            for (int fm = 0; fm < 2; ++fm)
                af[fm] = gen_chunk(xsl[cur][inp * 64 + fm * 32 + l31]);
#pragma unroll
            for (int fm = 0; fm < 2; ++fm)
#pragma unroll
                for (int fn = 0; fn < 2; ++fn)
                    acc[fm][fn] = __builtin_amdgcn_mfma_f32_32x32x16_bf16(
                        af[fm], bfr[fn], acc[fm][fn], 0, 0, 0);
        }
    }
#undef STAGE

    // ---- epilogue: reduce the 2 K-halves through LDS (reuse Bs), store ----
    float* rbuf = (float*)&Bs[0][0][0];
    int base = (wn * 64 + lane) * RSTR;
    __syncthreads();                 // everyone done reading Bs
    if (kk == 1) {
#pragma unroll
        for (int fm = 0; fm < 2; ++fm)
#pragma unroll
            for (int fn = 0; fn < 2; ++fn)
#pragma unroll
                for (int r = 0; r < 16; ++r)
                    rbuf[base + (fm * 2 + fn) * 16 + r] = acc[fm][fn][r];
    }
    __syncthreads();
    if (kk == 0) {
        // C/D layout (32x32): col = lane&31, row = (r&3) + 8*(r>>2) + 4*(lane>>5)
#pragma unroll
        for (int fn = 0; fn < 2; ++fn) {
            int o = o0 + wn * 64 + fn * 32 + l31;
            float bv = bias[o];
#pragma unroll
            for (int fm = 0; fm < 2; ++fm) {
#pragma unroll
                for (int r = 0; r < 16; ++r) {
                    float v = acc[fm][fn][r] + rbuf[base + (fm * 2 + fn) * 16 + r] + bv;
                    int token = m0 + fm * 32 + (r & 3) + 8 * (r >> 2) + 4 * half;
                    out[(size_t)token * OUT_FEAT + o] = v;
                }
            }
        }
    }
}

extern "C" void kernel_launch(void* const* d_in, const int* in_sizes, int n_in,
                              void* d_out, int out_size, void* d_ws, size_t ws_size,
                              hipStream_t stream) {
    const float* x            = (const float*)d_in[0];
    const float* coeff        = (const float*)d_in[1];
    const float* scale_base   = (const float*)d_in[2];
    const float* scale_spline = (const float*)d_in[3];
    const float* base_bias    = (const float*)d_in[4];
    float* out = (float*)d_out;

    short* Wb   = (short*)d_ws;                                  // 4 MB
    float* bias = (float*)((char*)d_ws + (size_t)OUT_FEAT * KDIM * 2);

    kan_prep<<<OUT_FEAT, 256, 0, stream>>>(coeff, scale_base, scale_spline, base_bias, Wb, bias);
    kan_gemm9<<<(NTOK / 64) * (OUT_FEAT / 128), 256, 0, stream>>>(x, Wb, bias, out);
}